// Round 5
// baseline (970.918 us; speedup 1.0000x reference)
//
#include <hip/hip_runtime.h>

// Distmult train forward:
//   scores[b] = sum_d head[b,d] * rel_embeds[rel_ids[b], d] * tail[b,d]
//   out[b]    = sigmoid( b < n_pos ? min(scores[b], upper[b]) : max(scores[b], lower[b-n_pos]) )
//
// B = 524288, D = 256. Memory-bound: streams head+tail (1 GiB) once -> ~185 us
// roofline at 6.3 TB/s. One wave (64 lanes) per row: lane i loads float4 #i of
// the 1 KiB row (16 B/lane, perfectly coalesced); rel row gather is wave-uniform
// and L2-resident (table is 512 KiB). Each wave owns a CONTIGUOUS chunk of rows
// so bounds reads / out writes have within-wave cacheline locality (no cross-XCD
// partial-line sharing). head/tail are single-use -> nontemporal loads keep the
// rel table hot in L2.

typedef float f32x4 __attribute__((ext_vector_type(4)));

__global__ __launch_bounds__(256) void distmult_fwd(
    const f32x4* __restrict__ head,   // [B, 64] as float4
    const f32x4* __restrict__ tail,   // [B, 64] as float4
    const int*   __restrict__ rel_ids,
    const float* __restrict__ lower,  // [n_neg]
    const float* __restrict__ upper,  // [n_pos]
    const f32x4* __restrict__ rel,    // [NUM_REL, 64] as float4
    float*       __restrict__ out,    // [B]
    int n_rows, int n_pos, int rows_per_wave)
{
    const int lane = threadIdx.x & 63;
    const int wave = (int)((blockIdx.x * blockDim.x + threadIdx.x) >> 6);

    int row = wave * rows_per_wave;
    int end = row + rows_per_wave;
    if (end > n_rows) end = n_rows;

    #pragma unroll 2
    for (; row < end; ++row) {
        // rel id is wave-uniform (one row per wave) -> scalarize the gather
        const int rid = __builtin_amdgcn_readfirstlane(rel_ids[row]);

        const size_t rbase = (size_t)row * 64 + lane;
        f32x4 h = __builtin_nontemporal_load(&head[rbase]);
        f32x4 t = __builtin_nontemporal_load(&tail[rbase]);
        f32x4 r = rel[(size_t)rid * 64 + lane];

        float p = h.x * r.x * t.x;
        p = fmaf(h.y * r.y, t.y, p);
        p = fmaf(h.z * r.z, t.z, p);
        p = fmaf(h.w * r.w, t.w, p);

        // 64-lane butterfly reduction
        #pragma unroll
        for (int m = 32; m; m >>= 1) p += __shfl_xor(p, m, 64);

        if (lane == 0) {
            float s = (row < n_pos) ? fminf(p, upper[row])
                                    : fmaxf(p, lower[row - n_pos]);
            out[row] = 1.0f / (1.0f + __expf(-s));
        }
    }
}

extern "C" void kernel_launch(void* const* d_in, const int* in_sizes, int n_in,
                              void* d_out, int out_size, void* d_ws, size_t ws_size,
                              hipStream_t stream)
{
    const f32x4* head  = (const f32x4*)d_in[0];
    const f32x4* tail  = (const f32x4*)d_in[1];
    const int*   rids  = (const int*)  d_in[2];
    const float* lower = (const float*)d_in[3];
    const float* upper = (const float*)d_in[4];
    const f32x4* rel   = (const f32x4*)d_in[5];
    float*       out   = (float*)d_out;

    const int n_rows = in_sizes[2];   // B
    const int n_pos  = in_sizes[4];   // |upper_bound|

    // G11: memory-bound -> ~2048 blocks (8 per CU), contiguous chunk per wave.
    const int n_blocks = 2048;
    const int n_waves  = n_blocks * 4;                    // 256 threads = 4 waves
    const int rpw      = (n_rows + n_waves - 1) / n_waves; // 64 at B=524288
    distmult_fwd<<<n_blocks, 256, 0, stream>>>(head, tail, rids, lower, upper,
                                               rel, out, n_rows, n_pos, rpw);
}